// Round 5
// baseline (259.152 us; speedup 1.0000x reference)
//
#include <hip/hip_runtime.h>
#include <math.h>

#define D_MODEL 1024
#define N_STATE 64
#define BATCH   16
#define SEQ     1024
#define CS      16          // scan steps per LDS chunk
#define SEGLEN  512         // steps stored per segment
#define WARM    64          // warmup steps for segment 1 (0.7311^64 ~ 2e-9)
#define SAT_T   1.0001f     // saturation margin (covers fp32 rounding)
#define LPS     20          // lpxT row stride (pad; rows stay 16B-aligned)

__device__ __forceinline__ float sigmoidf_dev(float v) {
    return 1.0f / (1.0f + expf(-v));
}

// DPP add: v += v[partner] within an aligned 16-lane row. Pure VALU, no LDS.
// 0xB1 = quad_perm [1,0,3,2] (xor1), 0x4E = quad_perm [2,3,0,1] (xor2),
// 0x141 = row_half_mirror (acts as xor4 on quad-uniform values),
// 0x140 = row_mirror (acts as xor8 on half-row-uniform values).
template<int CTRL>
__device__ __forceinline__ float dpp_add(float v) {
    int s = __builtin_amdgcn_update_dpp(0, __float_as_int(v), CTRL, 0xF, 0xF, true);
    return v + __int_as_float(s);
}

template<int CTRL>
__device__ __forceinline__ float dpp_min(float v) {
    int s = __builtin_amdgcn_update_dpp(0, __float_as_int(v), CTRL, 0xF, 0xF, true);
    return fminf(v, __int_as_float(s));
}

#define CLAMP01(v) __builtin_amdgcn_fmed3f((v), 0.0f, 1.0f)

// ---------------------------------------------------------------------------
// k0: precompute sigmoid(A) [D,N], sigmoid(W_B)^T -> BwT [D,N],
//     sigmoid(W_C) [D,N], sigmoid(gamma) [D]
// ---------------------------------------------------------------------------
__global__ __launch_bounds__(256) void k0_precompute(
        const float* __restrict__ A, const float* __restrict__ W_B,
        const float* __restrict__ W_C, const float* __restrict__ gamma,
        float* __restrict__ A_sig, float* __restrict__ BwT,
        float* __restrict__ Cs, float* __restrict__ gs) {
    int i = blockIdx.x * 256 + threadIdx.x;
    if (i < D_MODEL * N_STATE) {
        A_sig[i] = sigmoidf_dev(A[i]);
        Cs[i]    = sigmoidf_dev(W_C[i]);
        int d = i >> 6, n = i & 63;                  // i = d*64 + n
        BwT[i] = sigmoidf_dev(W_B[n * D_MODEL + d]); // W_B is [N, D]
        if (i < D_MODEL) gs[i] = sigmoidf_dev(gamma[i]);
    }
}

// ---------------------------------------------------------------------------
// k0b: csum[d] = sum_n Cs[d][n], in EXACTLY the op order of k2's slow path
// with h==1: per-quad (c0+c1)+(c2+c3), then balanced XOR tree off=1,2,4,8
// over the 16 quad sums (replicates the DPP tree bitwise). k3 substitutes
// csum[d] for every saturated element, so bit-match with k2's slow path
// keeps the final output bitwise identical.
// ---------------------------------------------------------------------------
__global__ __launch_bounds__(256) void k0b_csum(
        const float* __restrict__ Cs, float* __restrict__ csum) {
    int d = blockIdx.x * 256 + threadIdx.x;
    if (d >= D_MODEL) return;
    const float4* c = (const float4*)(Cs + (size_t)d * N_STATE);
    float w[16];
#pragma unroll
    for (int q = 0; q < 16; ++q) {
        float4 v = c[q];
        w[q] = (v.x + v.y) + (v.z + v.w);
    }
#pragma unroll
    for (int off = 1; off < 16; off <<= 1) {
        float tmp[16];
#pragma unroll
        for (int q = 0; q < 16; ++q) tmp[q] = w[q] + w[q ^ off];
#pragma unroll
        for (int q = 0; q < 16; ++q) w[q] = tmp[q];
    }
    csum[d] = w[0];
}

// ---------------------------------------------------------------------------
// k1: bt[m][n] = sum_d x[m][d] * BwT[d][n]  (M=16384, K=1024, N=64, fp32)
// Round 5: B operand held in REGISTERS (breg[16] float4 per thread, loaded
// from L1/L2-hot BwT with 16-lane broadcast) — eliminates the bs LDS stream
// that made round 4 LDS-throughput-bound (measured 69 us == predicted LDS
// cycle count). LDS now carries only the 32x16 x-tile (4.6 KB, dbuf).
// Mtile=32, Ktile=16, grid 512 (2 blk/CU), 2m x 4n per thread.
// k-order per output (kt 0..63 x kk 0..15 = k 0..1023 sequential, same fmaf)
// identical to round 4 -> bt, btmin bitwise identical.
// ---------------------------------------------------------------------------
__global__ __launch_bounds__(256) void k1_bt_gemm(
        const float* __restrict__ x, const float* __restrict__ BwT,
        float* __restrict__ bt, float* __restrict__ btmin) {
    __shared__ float xs[2][16][36];   // [buf][k][m], +4 pad (writes 2-way = free)

    const int t  = threadIdx.x;
    const int r  = t >> 4;            // 0..15 -> m rows r*2, r*2+1
    const int c  = t & 15;            // 0..15 -> n quad c*4
    const int m0 = blockIdx.x * 32;

    const int sm = t >> 3;            // staging: m row 0..31
    const int sk = (t & 7) * 2;       // staging: k pair 0..14

    float acc[2][4];
#pragma unroll
    for (int i = 0; i < 2; ++i)
#pragma unroll
        for (int j = 0; j < 4; ++j) acc[i][j] = 0.0f;

    // stage tile 0 into buf 0
    {
        float2 xv = *(const float2*)(x + (size_t)(m0 + sm) * D_MODEL + sk);
        xs[0][sk + 0][sm] = xv.x;
        xs[0][sk + 1][sm] = xv.y;
    }
    __syncthreads();

    for (int kt = 0; kt < 64; ++kt) {
        const int p = kt & 1;
        const bool more = (kt + 1 < 64);

        // B columns for this tile: 16 float4 loads, address uniform across
        // the 16 lanes sharing c (broadcast); BwT is L1/L2 resident.
        float4 breg[16];
#pragma unroll
        for (int kk = 0; kk < 16; ++kk)
            breg[kk] = *(const float4*)(BwT + (size_t)(kt * 16 + kk) * N_STATE + c * 4);

        // prefetch next x tile into registers
        float2 xv;
        if (more)
            xv = *(const float2*)(x + (size_t)(m0 + sm) * D_MODEL + (kt + 1) * 16 + sk);

#pragma unroll
        for (int kk = 0; kk < 16; ++kk) {
            float2 ap = *(const float2*)(&xs[p][kk][r * 2]);
            acc[0][0] = fmaf(ap.x, breg[kk].x, acc[0][0]);
            acc[0][1] = fmaf(ap.x, breg[kk].y, acc[0][1]);
            acc[0][2] = fmaf(ap.x, breg[kk].z, acc[0][2]);
            acc[0][3] = fmaf(ap.x, breg[kk].w, acc[0][3]);
            acc[1][0] = fmaf(ap.y, breg[kk].x, acc[1][0]);
            acc[1][1] = fmaf(ap.y, breg[kk].y, acc[1][1]);
            acc[1][2] = fmaf(ap.y, breg[kk].z, acc[1][2]);
            acc[1][3] = fmaf(ap.y, breg[kk].w, acc[1][3]);
        }

        if (more) {
            const int q = 1 - p;
            xs[q][sk + 0][sm] = xv.x;
            xs[q][sk + 1][sm] = xv.y;
        }
        __syncthreads();
    }

#pragma unroll
    for (int i = 0; i < 2; ++i) {
        float4 o = make_float4(acc[i][0], acc[i][1], acc[i][2], acc[i][3]);
        *(float4*)(&bt[(size_t)(m0 + r * 2 + i) * N_STATE + c * 4]) = o;
    }

    // btmin: per-thread min of its 4 n's, then DPP min across the aligned
    // 16-lane row (lanes sharing r). Same tree as rounds 3/4 -> bitwise same.
    float bm0 = fminf(fminf(acc[0][0], acc[0][1]), fminf(acc[0][2], acc[0][3]));
    float bm1 = fminf(fminf(acc[1][0], acc[1][1]), fminf(acc[1][2], acc[1][3]));
    bm0 = dpp_min<0xB1>(bm0); bm0 = dpp_min<0x4E>(bm0);
    bm0 = dpp_min<0x141>(bm0); bm0 = dpp_min<0x140>(bm0);
    bm1 = dpp_min<0xB1>(bm1); bm1 = dpp_min<0x4E>(bm1);
    bm1 = dpp_min<0x141>(bm1); bm1 = dpp_min<0x140>(bm1);
    if (c == 0) {
        btmin[m0 + r * 2]     = bm0;
        btmin[m0 + r * 2 + 1] = bm1;
    }
}

// ---------------------------------------------------------------------------
// k2: sequential scan, time-segmented 2x. grid 2048 = 16 batch x 64 dgroup x
// 2 segments -> 8 blocks/CU, 32 waves/CU.
// Saturation fast path (round-3, verified): pred(s,d) = x*max(btmin,0) >=
// SAT_T => h clamps to exactly 1.0f, y bitwise csum[d]; k2 stores only
// pred-false rows (~0.4%), k3 reconstructs the rest.
// Round 4: px transposed [chain][LPS]; 4-step groups take ONE float4 read +
// 3 min + 1 vote when the wave's quad is all-fast (~94%), falling back to
// the identical per-step path for mixed quads.
// ---------------------------------------------------------------------------
__global__ __launch_bounds__(256, 8) void k2_scan(
        const float* __restrict__ x, const float* __restrict__ bt,
        const float* __restrict__ btmin,
        const float* __restrict__ A_sig, const float* __restrict__ Cs,
        float* __restrict__ y_raw) {
    const int t    = threadIdx.x;
    const int lane = t & 63;
    const int wv   = t >> 6;
    const int nq   = lane & 15;            // n-quad -> n = nq*4
    const int cl   = wv * 4 + (lane >> 4); // chain within block, 0..15
    const int bid  = blockIdx.x;
    const int seg  = bid & 1;
    const int dg   = (bid >> 1) & 63;
    const int b    = bid >> 7;
    const int d0   = dg * 16;
    const int d    = d0 + cl;

    const int nWarm  = seg ? (WARM / CS) : 0;     // 4 or 0
    const int nTot   = nWarm + (SEGLEN / CS);     // 36 or 32
    const int sStart = seg * SEGLEN - nWarm * CS; // 0 or 448

    __shared__ __align__(16) float lbt [2][CS * 64];    // 2 x 4 KB bt tile
    __shared__ __align__(16) float lx  [2][CS * 16];    // 2 x 1 KB x[step][chain]
    __shared__ __align__(16) float lpxT[2][16 * LPS];   // 2 x 1.25 KB px[chain][step(+pad)]

    const float4 av = *(const float4*)(A_sig + (size_t)d * N_STATE + nq * 4);
    const float4 cv = *(const float4*)(Cs    + (size_t)d * N_STATE + nq * 4);

    float h0 = 0.f, h1 = 0.f, h2 = 0.f, h3 = 0.f;

    const float* btp  = bt    + (size_t)b * SEQ * N_STATE + (size_t)sStart * N_STATE;
    const float* btmp = btmin + (size_t)b * SEQ + sStart;
    const float* xpp  = x + (size_t)b * SEQ * D_MODEL + (size_t)sStart * D_MODEL + d0;
    float* ystore = y_raw + (size_t)b * SEQ * D_MODEL + (size_t)seg * SEGLEN * D_MODEL + d;

    const int xst = t >> 4;          // staging: step 0..15
    const int xdd = t & 15;          // staging: chain

    // stage chunk 0 into buf 0
    {
        float4 b4 = *(const float4*)(btp + t * 4);
        float  xv = xpp[(size_t)xst * D_MODEL + xdd];
        float  bm = fmaxf(btmp[xst], 0.f);   // clamp: pred => bm>0 and x>0
        *(float4*)(&lbt[0][t * 4]) = b4;
        lx[0][t] = xv;
        lpxT[0][xdd * LPS + xst] = xv * bm;
    }
    btp  += CS * N_STATE;
    btmp += CS;
    xpp  += (size_t)CS * D_MODEL;
    __syncthreads();

    for (int ch = 0; ch < nTot; ++ch) {
        const int p = ch & 1;
        float4 nb; float nx, npx;
        const bool more = (ch + 1 < nTot);
        if (more) {
            nb  = *(const float4*)(btp + t * 4);
            nx  = xpp[(size_t)xst * D_MODEL + xdd];
            npx = nx * fmaxf(btmp[xst], 0.f);
            btp  += CS * N_STATE;
            btmp += CS;
            xpp  += (size_t)CS * D_MODEL;
        }

        const float* Lb = lbt[p];
        const float* Lx = lx [p];
        const float* Lp = &lpxT[p][cl * LPS];   // this lane's chain, 16 steps

        if (ch < nWarm) {
#pragma unroll
            for (int g = 0; g < 4; ++g) {
                const float4 pq = *(const float4*)(Lp + g * 4);
                const float qmin = fminf(fminf(pq.x, pq.y), fminf(pq.z, pq.w));
                if (__all(qmin >= SAT_T)) { h0 = h1 = h2 = h3 = 1.f; continue; }
                const float pmv[4] = {pq.x, pq.y, pq.z, pq.w};
#pragma unroll
                for (int j = 0; j < 4; ++j) {
                    const int i = g * 4 + j;
                    const float pm = pmv[j];
                    if (__all(pm >= SAT_T)) { h0 = h1 = h2 = h3 = 1.f; continue; }
                    const float  xt = Lx[i * 16 + cl];
                    const float4 bv = *(const float4*)(Lb + i * 64 + nq * 4);
                    h0 = CLAMP01(fmaf(h0, av.x, bv.x * xt));
                    h1 = CLAMP01(fmaf(h1, av.y, bv.y * xt));
                    h2 = CLAMP01(fmaf(h2, av.z, bv.z * xt));
                    h3 = CLAMP01(fmaf(h3, av.w, bv.w * xt));
                }
            }
        } else {
#pragma unroll
            for (int g = 0; g < 4; ++g) {
                const float4 pq = *(const float4*)(Lp + g * 4);
                const float qmin = fminf(fminf(pq.x, pq.y), fminf(pq.z, pq.w));
                if (__all(qmin >= SAT_T)) { h0 = h1 = h2 = h3 = 1.f; continue; }
                const float pmv[4] = {pq.x, pq.y, pq.z, pq.w};
#pragma unroll
                for (int j = 0; j < 4; ++j) {
                    const int i = g * 4 + j;
                    const float pm = pmv[j];
                    if (__all(pm >= SAT_T)) { h0 = h1 = h2 = h3 = 1.f; continue; }
                    const float  xt = Lx[i * 16 + cl];
                    const float4 bv = *(const float4*)(Lb + i * 64 + nq * 4);
                    h0 = CLAMP01(fmaf(h0, av.x, bv.x * xt));
                    h1 = CLAMP01(fmaf(h1, av.y, bv.y * xt));
                    h2 = CLAMP01(fmaf(h2, av.z, bv.z * xt));
                    h3 = CLAMP01(fmaf(h3, av.w, bv.w * xt));
                    float y = fmaf(h0, cv.x, h1 * cv.y) + fmaf(h2, cv.z, h3 * cv.w);
                    y = dpp_add<0xB1>(y);
                    y = dpp_add<0x4E>(y);
                    y = dpp_add<0x141>(y);
                    y = dpp_add<0x140>(y);
                    // store only pred-false rows (row-uniform condition);
                    // pred-true rows are reconstructed as csum[d] in k3.
                    if (nq == 0 && !(pm >= SAT_T)) ystore[(size_t)i * D_MODEL] = y;
                }
            }
            ystore += (size_t)CS * D_MODEL;
        }

        if (more) {
            const int q = 1 - p;
            *(float4*)(&lbt[q][t * 4]) = nb;
            lx[q][t] = nx;
            lpxT[q][xdd * LPS + xst] = npx;
        }
        __syncthreads();
    }
}

// ---------------------------------------------------------------------------
// k3: per (b,s) row of 1024: reconstruct y (pred ? csum[d] : stored y_raw),
// two-pass layernorm over d, scale by gs, add residual x, clip. In-place.
// Single conditional float4 load (taken by ~1.6% of lanes).
// ---------------------------------------------------------------------------
__global__ __launch_bounds__(256, 1) void k3_norm(
        const float* __restrict__ x, const float* __restrict__ gs,
        const float* __restrict__ btmin, const float* __restrict__ csum,
        float* __restrict__ y) {
    const int row = blockIdx.x;           // b*SEQ + s
    const int t   = threadIdx.x;
    const size_t base = (size_t)row * D_MODEL + t * 4;
    const float bm = fmaxf(btmin[row], 0.f);   // same clamp+product as k2

    float4 xv  = *(const float4*)(x + base);
    float4 cs4 = *(const float4*)(csum + t * 4);
    const bool p0 = (xv.x * bm >= SAT_T);
    const bool p1 = (xv.y * bm >= SAT_T);
    const bool p2 = (xv.z * bm >= SAT_T);
    const bool p3 = (xv.w * bm >= SAT_T);
    float y0 = cs4.x, y1 = cs4.y, y2 = cs4.z, y3 = cs4.w;
    if (!(p0 && p1 && p2 && p3)) {
        float4 ld = *(const float4*)(y + base);
        if (!p0) y0 = ld.x;
        if (!p1) y1 = ld.y;
        if (!p2) y2 = ld.z;
        if (!p3) y3 = ld.w;
    }

    float s1 = (y0 + y1) + (y2 + y3);
#pragma unroll
    for (int off = 32; off > 0; off >>= 1) s1 += __shfl_xor(s1, off);

    __shared__ float red[8];
    const int w = t >> 6;
    if ((t & 63) == 0) red[w] = s1;
    __syncthreads();
    const float mu = (red[0] + red[1] + red[2] + red[3]) * (1.0f / (float)D_MODEL);

    const float dx0 = y0 - mu, dx1 = y1 - mu, dx2 = y2 - mu, dx3 = y3 - mu;
    float s2 = (dx0 * dx0 + dx1 * dx1) + (dx2 * dx2 + dx3 * dx3);
#pragma unroll
    for (int off = 32; off > 0; off >>= 1) s2 += __shfl_xor(s2, off);
    if ((t & 63) == 0) red[4 + w] = s2;
    __syncthreads();
    const float var = (red[4] + red[5] + red[6] + red[7]) * (1.0f / (float)D_MODEL);
    const float rs  = 1.0f / sqrtf(var + 1e-5f);

    float4 gv = *(const float4*)(gs + t * 4);
    float4 o;
    o.x = fminf(fmaxf(dx0 * rs * gv.x + xv.x, 0.f), 1.f);
    o.y = fminf(fmaxf(dx1 * rs * gv.y + xv.y, 0.f), 1.f);
    o.z = fminf(fmaxf(dx2 * rs * gv.z + xv.z, 0.f), 1.f);
    o.w = fminf(fmaxf(dx3 * rs * gv.w + xv.w, 0.f), 1.f);
    *(float4*)(y + base) = o;
}

// ---------------------------------------------------------------------------
extern "C" void kernel_launch(void* const* d_in, const int* in_sizes, int n_in,
                              void* d_out, int out_size, void* d_ws, size_t ws_size,
                              hipStream_t stream) {
    (void)in_sizes; (void)n_in; (void)out_size; (void)ws_size;
    const float* x     = (const float*)d_in[0];
    const float* A     = (const float*)d_in[1];
    const float* W_B   = (const float*)d_in[2];
    const float* W_C   = (const float*)d_in[3];
    const float* gamma = (const float*)d_in[4];
    float* out = (float*)d_out;
    float* ws  = (float*)d_ws;

    float* bt    = ws;                                       // 1048576 floats
    float* A_sig = ws + 1048576;                             // 65536
    float* BwT   = ws + 1048576 + 65536;                     // 65536
    float* Cs    = ws + 1048576 + 2 * 65536;                 // 65536
    float* gs    = ws + 1048576 + 3 * 65536;                 // 1024
    float* btmin = ws + 1048576 + 3 * 65536 + 1024;          // 16384
    float* csum  = ws + 1048576 + 3 * 65536 + 1024 + 16384;  // 1024

    k0_precompute<<<dim3(256), dim3(256), 0, stream>>>(A, W_B, W_C, gamma,
                                                       A_sig, BwT, Cs, gs);
    k0b_csum<<<dim3(4), dim3(256), 0, stream>>>(Cs, csum);
    k1_bt_gemm<<<dim3(512), dim3(256), 0, stream>>>(x, BwT, bt, btmin);
    k2_scan<<<dim3(2048), dim3(256), 0, stream>>>(x, bt, btmin, A_sig, Cs, out);
    k3_norm<<<dim3(BATCH * SEQ), dim3(256), 0, stream>>>(x, gs, btmin, csum, out);
}

// Round 6
// 221.741 us; speedup vs baseline: 1.1687x; 1.1687x over previous
//
#include <hip/hip_runtime.h>
#include <math.h>

#define D_MODEL 1024
#define N_STATE 64
#define BATCH   16
#define SEQ     1024
#define CS      16          // scan steps per LDS chunk
#define SEGLEN  512         // steps stored per segment
#define WARM    64          // warmup steps for segment 1 (0.7311^64 ~ 2e-9)
#define SAT_T   1.0001f     // saturation margin (covers fp32 rounding)
#define LPS     20          // lpxT row stride (pad; rows stay 16B-aligned)

__device__ __forceinline__ float sigmoidf_dev(float v) {
    return 1.0f / (1.0f + expf(-v));
}

// DPP add: v += v[partner] within an aligned 16-lane row. Pure VALU, no LDS.
// 0xB1 = quad_perm [1,0,3,2] (xor1), 0x4E = quad_perm [2,3,0,1] (xor2),
// 0x141 = row_half_mirror (acts as xor4 on quad-uniform values),
// 0x140 = row_mirror (acts as xor8 on half-row-uniform values).
template<int CTRL>
__device__ __forceinline__ float dpp_add(float v) {
    int s = __builtin_amdgcn_update_dpp(0, __float_as_int(v), CTRL, 0xF, 0xF, true);
    return v + __int_as_float(s);
}

template<int CTRL>
__device__ __forceinline__ float dpp_min(float v) {
    int s = __builtin_amdgcn_update_dpp(0, __float_as_int(v), CTRL, 0xF, 0xF, true);
    return fminf(v, __int_as_float(s));
}

#define CLAMP01(v) __builtin_amdgcn_fmed3f((v), 0.0f, 1.0f)

// ---------------------------------------------------------------------------
// k0: precompute sigmoid(A) [D,N], sigmoid(W_B)^T -> BwT [D,N],
//     sigmoid(W_C) [D,N], sigmoid(gamma) [D]
// ---------------------------------------------------------------------------
__global__ __launch_bounds__(256) void k0_precompute(
        const float* __restrict__ A, const float* __restrict__ W_B,
        const float* __restrict__ W_C, const float* __restrict__ gamma,
        float* __restrict__ A_sig, float* __restrict__ BwT,
        float* __restrict__ Cs, float* __restrict__ gs) {
    int i = blockIdx.x * 256 + threadIdx.x;
    if (i < D_MODEL * N_STATE) {
        A_sig[i] = sigmoidf_dev(A[i]);
        Cs[i]    = sigmoidf_dev(W_C[i]);
        int d = i >> 6, n = i & 63;                  // i = d*64 + n
        BwT[i] = sigmoidf_dev(W_B[n * D_MODEL + d]); // W_B is [N, D]
        if (i < D_MODEL) gs[i] = sigmoidf_dev(gamma[i]);
    }
}

// ---------------------------------------------------------------------------
// k0b: csum[d] = sum_n Cs[d][n], in EXACTLY the op order of k2's slow path
// with h==1: per-quad (c0+c1)+(c2+c3), then balanced XOR tree off=1,2,4,8
// over the 16 quad sums (replicates the DPP tree bitwise). k3 substitutes
// csum[d] for every saturated element, so bit-match with k2's slow path
// keeps the final output bitwise identical.
// ---------------------------------------------------------------------------
__global__ __launch_bounds__(256) void k0b_csum(
        const float* __restrict__ Cs, float* __restrict__ csum) {
    int d = blockIdx.x * 256 + threadIdx.x;
    if (d >= D_MODEL) return;
    const float4* c = (const float4*)(Cs + (size_t)d * N_STATE);
    float w[16];
#pragma unroll
    for (int q = 0; q < 16; ++q) {
        float4 v = c[q];
        w[q] = (v.x + v.y) + (v.z + v.w);
    }
#pragma unroll
    for (int off = 1; off < 16; off <<= 1) {
        float tmp[16];
#pragma unroll
        for (int q = 0; q < 16; ++q) tmp[q] = w[q] + w[q ^ off];
#pragma unroll
        for (int q = 0; q < 16; ++q) w[q] = tmp[q];
    }
    csum[d] = w[0];
}

// ---------------------------------------------------------------------------
// k1: bt[m][n] = sum_d x[m][d] * BwT[d][n]  (M=16384, K=1024, N=64, fp32)
// Round 6: k1 is LDS register-delivery bound (broadcast does NOT reduce
// ds_read cost: a wave b128 read delivers 1 KB to VGPRs regardless; m134:
// ~85 B/cyc/CU). Per-thread tile Mr x Nr costs 4(Mr+Nr) LDS bytes per
// Mr*Nr FMA; round-4's 2x4 = 3 B/FMA -> 3.2 GB -> ~60 us (matches 69
// measured). This version: Mr=4 x Nr=4 (2 B/FMA, 2.1 GB ~ 40 us bound),
// Mtile=64, block 256, grid 256 -> exactly 1 block/CU, 4 waves/CU (fills
// all 4 SIMDs; more waves/CU would only add redundant B reads).
// k-order per output: kt 0..63 x kk 0..15 = k 0..1023 sequential fmaf ->
// bt, btmin bitwise identical to rounds 3-5.
// ---------------------------------------------------------------------------
__global__ __launch_bounds__(256) void k1_bt_gemm(
        const float* __restrict__ x, const float* __restrict__ BwT,
        float* __restrict__ bt, float* __restrict__ btmin) {
    __shared__ float xs[2][16][68];   // [buf][k][m(64)+4 pad]
    __shared__ float bs[2][16][64];   // [buf][k][n]

    const int t  = threadIdx.x;
    const int r  = t >> 4;            // 0..15 -> m rows r*4 .. r*4+3
    const int c  = t & 15;            // 0..15 -> n quad c*4
    const int m0 = blockIdx.x * 64;

    const int sm  = t >> 2;           // staging: m row 0..63
    const int sk4 = (t & 3) * 4;      // staging: k quad 0,4,8,12

    float acc[4][4];
#pragma unroll
    for (int i = 0; i < 4; ++i)
#pragma unroll
        for (int j = 0; j < 4; ++j) acc[i][j] = 0.0f;

    // stage tile 0 into buf 0
    {
        float4 xv = *(const float4*)(x + (size_t)(m0 + sm) * D_MODEL + sk4);
        float4 bv = *(const float4*)(BwT + t * 4);
        xs[0][sk4 + 0][sm] = xv.x;
        xs[0][sk4 + 1][sm] = xv.y;
        xs[0][sk4 + 2][sm] = xv.z;
        xs[0][sk4 + 3][sm] = xv.w;
        *(float4*)(&bs[0][0][0] + t * 4) = bv;
    }
    __syncthreads();

    for (int kt = 0; kt < 64; ++kt) {
        const int p = kt & 1;
        const bool more = (kt + 1 < 64);
        float4 xv, bv;
        if (more) {
            const int k0 = (kt + 1) * 16;
            xv = *(const float4*)(x + (size_t)(m0 + sm) * D_MODEL + k0 + sk4);
            bv = *(const float4*)(BwT + (size_t)k0 * N_STATE + t * 4);
        }

#pragma unroll
        for (int kk = 0; kk < 16; ++kk) {
            const float4 ap = *(const float4*)(&xs[p][kk][r * 4]);
            const float4 bq = *(const float4*)(&bs[p][kk][c * 4]);
            acc[0][0] = fmaf(ap.x, bq.x, acc[0][0]);
            acc[0][1] = fmaf(ap.x, bq.y, acc[0][1]);
            acc[0][2] = fmaf(ap.x, bq.z, acc[0][2]);
            acc[0][3] = fmaf(ap.x, bq.w, acc[0][3]);
            acc[1][0] = fmaf(ap.y, bq.x, acc[1][0]);
            acc[1][1] = fmaf(ap.y, bq.y, acc[1][1]);
            acc[1][2] = fmaf(ap.y, bq.z, acc[1][2]);
            acc[1][3] = fmaf(ap.y, bq.w, acc[1][3]);
            acc[2][0] = fmaf(ap.z, bq.x, acc[2][0]);
            acc[2][1] = fmaf(ap.z, bq.y, acc[2][1]);
            acc[2][2] = fmaf(ap.z, bq.z, acc[2][2]);
            acc[2][3] = fmaf(ap.z, bq.w, acc[2][3]);
            acc[3][0] = fmaf(ap.w, bq.x, acc[3][0]);
            acc[3][1] = fmaf(ap.w, bq.y, acc[3][1]);
            acc[3][2] = fmaf(ap.w, bq.z, acc[3][2]);
            acc[3][3] = fmaf(ap.w, bq.w, acc[3][3]);
        }

        if (more) {
            const int q = 1 - p;
            xs[q][sk4 + 0][sm] = xv.x;
            xs[q][sk4 + 1][sm] = xv.y;
            xs[q][sk4 + 2][sm] = xv.z;
            xs[q][sk4 + 3][sm] = xv.w;
            *(float4*)(&bs[q][0][0] + t * 4) = bv;
        }
        __syncthreads();
    }

#pragma unroll
    for (int i = 0; i < 4; ++i) {
        *(float4*)(&bt[(size_t)(m0 + r * 4 + i) * N_STATE + c * 4]) =
            make_float4(acc[i][0], acc[i][1], acc[i][2], acc[i][3]);
        // btmin: per-thread min of its 4 n's, then DPP min across the aligned
        // 16-lane row (lanes sharing r). Same tree as rounds 3-5 (fmin is
        // order-insensitive anyway) -> bitwise identical.
        float bm = fminf(fminf(acc[i][0], acc[i][1]), fminf(acc[i][2], acc[i][3]));
        bm = dpp_min<0xB1>(bm);  bm = dpp_min<0x4E>(bm);
        bm = dpp_min<0x141>(bm); bm = dpp_min<0x140>(bm);
        if (c == 0) btmin[m0 + r * 4 + i] = bm;
    }
}

// ---------------------------------------------------------------------------
// k2: sequential scan, time-segmented 2x. grid 2048 = 16 batch x 64 dgroup x
// 2 segments -> 8 blocks/CU, 32 waves/CU.
// Saturation fast path (round-3, verified): pred(s,d) = x*max(btmin,0) >=
// SAT_T => h clamps to exactly 1.0f, y bitwise csum[d]; k2 stores only
// pred-false rows (~0.4%), k3 reconstructs the rest.
// Round 4: px transposed [chain][LPS]; 4-step groups take ONE float4 read +
// 3 min + 1 vote when the wave's quad is all-fast (~94%), falling back to
// the identical per-step path for mixed quads.
// ---------------------------------------------------------------------------
__global__ __launch_bounds__(256, 8) void k2_scan(
        const float* __restrict__ x, const float* __restrict__ bt,
        const float* __restrict__ btmin,
        const float* __restrict__ A_sig, const float* __restrict__ Cs,
        float* __restrict__ y_raw) {
    const int t    = threadIdx.x;
    const int lane = t & 63;
    const int wv   = t >> 6;
    const int nq   = lane & 15;            // n-quad -> n = nq*4
    const int cl   = wv * 4 + (lane >> 4); // chain within block, 0..15
    const int bid  = blockIdx.x;
    const int seg  = bid & 1;
    const int dg   = (bid >> 1) & 63;
    const int b    = bid >> 7;
    const int d0   = dg * 16;
    const int d    = d0 + cl;

    const int nWarm  = seg ? (WARM / CS) : 0;     // 4 or 0
    const int nTot   = nWarm + (SEGLEN / CS);     // 36 or 32
    const int sStart = seg * SEGLEN - nWarm * CS; // 0 or 448

    __shared__ __align__(16) float lbt [2][CS * 64];    // 2 x 4 KB bt tile
    __shared__ __align__(16) float lx  [2][CS * 16];    // 2 x 1 KB x[step][chain]
    __shared__ __align__(16) float lpxT[2][16 * LPS];   // 2 x 1.25 KB px[chain][step(+pad)]

    const float4 av = *(const float4*)(A_sig + (size_t)d * N_STATE + nq * 4);
    const float4 cv = *(const float4*)(Cs    + (size_t)d * N_STATE + nq * 4);

    float h0 = 0.f, h1 = 0.f, h2 = 0.f, h3 = 0.f;

    const float* btp  = bt    + (size_t)b * SEQ * N_STATE + (size_t)sStart * N_STATE;
    const float* btmp = btmin + (size_t)b * SEQ + sStart;
    const float* xpp  = x + (size_t)b * SEQ * D_MODEL + (size_t)sStart * D_MODEL + d0;
    float* ystore = y_raw + (size_t)b * SEQ * D_MODEL + (size_t)seg * SEGLEN * D_MODEL + d;

    const int xst = t >> 4;          // staging: step 0..15
    const int xdd = t & 15;          // staging: chain

    // stage chunk 0 into buf 0
    {
        float4 b4 = *(const float4*)(btp + t * 4);
        float  xv = xpp[(size_t)xst * D_MODEL + xdd];
        float  bm = fmaxf(btmp[xst], 0.f);   // clamp: pred => bm>0 and x>0
        *(float4*)(&lbt[0][t * 4]) = b4;
        lx[0][t] = xv;
        lpxT[0][xdd * LPS + xst] = xv * bm;
    }
    btp  += CS * N_STATE;
    btmp += CS;
    xpp  += (size_t)CS * D_MODEL;
    __syncthreads();

    for (int ch = 0; ch < nTot; ++ch) {
        const int p = ch & 1;
        float4 nb; float nx, npx;
        const bool more = (ch + 1 < nTot);
        if (more) {
            nb  = *(const float4*)(btp + t * 4);
            nx  = xpp[(size_t)xst * D_MODEL + xdd];
            npx = nx * fmaxf(btmp[xst], 0.f);
            btp  += CS * N_STATE;
            btmp += CS;
            xpp  += (size_t)CS * D_MODEL;
        }

        const float* Lb = lbt[p];
        const float* Lx = lx [p];
        const float* Lp = &lpxT[p][cl * LPS];   // this lane's chain, 16 steps

        if (ch < nWarm) {
#pragma unroll
            for (int g = 0; g < 4; ++g) {
                const float4 pq = *(const float4*)(Lp + g * 4);
                const float qmin = fminf(fminf(pq.x, pq.y), fminf(pq.z, pq.w));
                if (__all(qmin >= SAT_T)) { h0 = h1 = h2 = h3 = 1.f; continue; }
                const float pmv[4] = {pq.x, pq.y, pq.z, pq.w};
#pragma unroll
                for (int j = 0; j < 4; ++j) {
                    const int i = g * 4 + j;
                    const float pm = pmv[j];
                    if (__all(pm >= SAT_T)) { h0 = h1 = h2 = h3 = 1.f; continue; }
                    const float  xt = Lx[i * 16 + cl];
                    const float4 bv = *(const float4*)(Lb + i * 64 + nq * 4);
                    h0 = CLAMP01(fmaf(h0, av.x, bv.x * xt));
                    h1 = CLAMP01(fmaf(h1, av.y, bv.y * xt));
                    h2 = CLAMP01(fmaf(h2, av.z, bv.z * xt));
                    h3 = CLAMP01(fmaf(h3, av.w, bv.w * xt));
                }
            }
        } else {
#pragma unroll
            for (int g = 0; g < 4; ++g) {
                const float4 pq = *(const float4*)(Lp + g * 4);
                const float qmin = fminf(fminf(pq.x, pq.y), fminf(pq.z, pq.w));
                if (__all(qmin >= SAT_T)) { h0 = h1 = h2 = h3 = 1.f; continue; }
                const float pmv[4] = {pq.x, pq.y, pq.z, pq.w};
#pragma unroll
                for (int j = 0; j < 4; ++j) {
                    const int i = g * 4 + j;
                    const float pm = pmv[j];
                    if (__all(pm >= SAT_T)) { h0 = h1 = h2 = h3 = 1.f; continue; }
                    const float  xt = Lx[i * 16 + cl];
                    const float4 bv = *(const float4*)(Lb + i * 64 + nq * 4);
                    h0 = CLAMP01(fmaf(h0, av.x, bv.x * xt));
                    h1 = CLAMP01(fmaf(h1, av.y, bv.y * xt));
                    h2 = CLAMP01(fmaf(h2, av.z, bv.z * xt));
                    h3 = CLAMP01(fmaf(h3, av.w, bv.w * xt));
                    float y = fmaf(h0, cv.x, h1 * cv.y) + fmaf(h2, cv.z, h3 * cv.w);
                    y = dpp_add<0xB1>(y);
                    y = dpp_add<0x4E>(y);
                    y = dpp_add<0x141>(y);
                    y = dpp_add<0x140>(y);
                    // store only pred-false rows (row-uniform condition);
                    // pred-true rows are reconstructed as csum[d] in k3.
                    if (nq == 0 && !(pm >= SAT_T)) ystore[(size_t)i * D_MODEL] = y;
                }
            }
            ystore += (size_t)CS * D_MODEL;
        }

        if (more) {
            const int q = 1 - p;
            *(float4*)(&lbt[q][t * 4]) = nb;
            lx[q][t] = nx;
            lpxT[q][xdd * LPS + xst] = npx;
        }
        __syncthreads();
    }
}

// ---------------------------------------------------------------------------
// k3: per (b,s) row of 1024: reconstruct y (pred ? csum[d] : stored y_raw),
// two-pass layernorm over d, scale by gs, add residual x, clip. In-place.
// Single conditional float4 load (taken by ~1.6% of lanes).
// ---------------------------------------------------------------------------
__global__ __launch_bounds__(256, 1) void k3_norm(
        const float* __restrict__ x, const float* __restrict__ gs,
        const float* __restrict__ btmin, const float* __restrict__ csum,
        float* __restrict__ y) {
    const int row = blockIdx.x;           // b*SEQ + s
    const int t   = threadIdx.x;
    const size_t base = (size_t)row * D_MODEL + t * 4;
    const float bm = fmaxf(btmin[row], 0.f);   // same clamp+product as k2

    float4 xv  = *(const float4*)(x + base);
    float4 cs4 = *(const float4*)(csum + t * 4);
    const bool p0 = (xv.x * bm >= SAT_T);
    const bool p1 = (xv.y * bm >= SAT_T);
    const bool p2 = (xv.z * bm >= SAT_T);
    const bool p3 = (xv.w * bm >= SAT_T);
    float y0 = cs4.x, y1 = cs4.y, y2 = cs4.z, y3 = cs4.w;
    if (!(p0 && p1 && p2 && p3)) {
        float4 ld = *(const float4*)(y + base);
        if (!p0) y0 = ld.x;
        if (!p1) y1 = ld.y;
        if (!p2) y2 = ld.z;
        if (!p3) y3 = ld.w;
    }

    float s1 = (y0 + y1) + (y2 + y3);
#pragma unroll
    for (int off = 32; off > 0; off >>= 1) s1 += __shfl_xor(s1, off);

    __shared__ float red[8];
    const int w = t >> 6;
    if ((t & 63) == 0) red[w] = s1;
    __syncthreads();
    const float mu = (red[0] + red[1] + red[2] + red[3]) * (1.0f / (float)D_MODEL);

    const float dx0 = y0 - mu, dx1 = y1 - mu, dx2 = y2 - mu, dx3 = y3 - mu;
    float s2 = (dx0 * dx0 + dx1 * dx1) + (dx2 * dx2 + dx3 * dx3);
#pragma unroll
    for (int off = 32; off > 0; off >>= 1) s2 += __shfl_xor(s2, off);
    if ((t & 63) == 0) red[4 + w] = s2;
    __syncthreads();
    const float var = (red[4] + red[5] + red[6] + red[7]) * (1.0f / (float)D_MODEL);
    const float rs  = 1.0f / sqrtf(var + 1e-5f);

    float4 gv = *(const float4*)(gs + t * 4);
    float4 o;
    o.x = fminf(fmaxf(dx0 * rs * gv.x + xv.x, 0.f), 1.f);
    o.y = fminf(fmaxf(dx1 * rs * gv.y + xv.y, 0.f), 1.f);
    o.z = fminf(fmaxf(dx2 * rs * gv.z + xv.z, 0.f), 1.f);
    o.w = fminf(fmaxf(dx3 * rs * gv.w + xv.w, 0.f), 1.f);
    *(float4*)(y + base) = o;
}

// ---------------------------------------------------------------------------
extern "C" void kernel_launch(void* const* d_in, const int* in_sizes, int n_in,
                              void* d_out, int out_size, void* d_ws, size_t ws_size,
                              hipStream_t stream) {
    (void)in_sizes; (void)n_in; (void)out_size; (void)ws_size;
    const float* x     = (const float*)d_in[0];
    const float* A     = (const float*)d_in[1];
    const float* W_B   = (const float*)d_in[2];
    const float* W_C   = (const float*)d_in[3];
    const float* gamma = (const float*)d_in[4];
    float* out = (float*)d_out;
    float* ws  = (float*)d_ws;

    float* bt    = ws;                                       // 1048576 floats
    float* A_sig = ws + 1048576;                             // 65536
    float* BwT   = ws + 1048576 + 65536;                     // 65536
    float* Cs    = ws + 1048576 + 2 * 65536;                 // 65536
    float* gs    = ws + 1048576 + 3 * 65536;                 // 1024
    float* btmin = ws + 1048576 + 3 * 65536 + 1024;          // 16384
    float* csum  = ws + 1048576 + 3 * 65536 + 1024 + 16384;  // 1024

    k0_precompute<<<dim3(256), dim3(256), 0, stream>>>(A, W_B, W_C, gamma,
                                                       A_sig, BwT, Cs, gs);
    k0b_csum<<<dim3(4), dim3(256), 0, stream>>>(Cs, csum);
    k1_bt_gemm<<<dim3(256), dim3(256), 0, stream>>>(x, BwT, bt, btmin);
    k2_scan<<<dim3(2048), dim3(256), 0, stream>>>(x, bt, btmin, A_sig, Cs, out);
    k3_norm<<<dim3(BATCH * SEQ), dim3(256), 0, stream>>>(x, gs, btmin, csum, out);
}

// Round 7
// 206.520 us; speedup vs baseline: 1.2549x; 1.0737x over previous
//
#include <hip/hip_runtime.h>
#include <math.h>

#define D_MODEL 1024
#define N_STATE 64
#define BATCH   16
#define SEQ     1024
#define CS      16          // scan steps per LDS chunk
#define SEGLEN  512         // steps stored per segment
#define WARM    64          // warmup steps for segment 1 (0.7311^64 ~ 2e-9)
#define SAT_T   1.0001f     // saturation margin (covers fp32 rounding)
#define LPS     20          // lpxT row stride (pad; rows stay 16B-aligned)

__device__ __forceinline__ float sigmoidf_dev(float v) {
    return 1.0f / (1.0f + expf(-v));
}

// DPP add: v += v[partner] within an aligned 16-lane row. Pure VALU, no LDS.
// 0xB1 = quad_perm [1,0,3,2] (xor1), 0x4E = quad_perm [2,3,0,1] (xor2),
// 0x141 = row_half_mirror (acts as xor4 on quad-uniform values),
// 0x140 = row_mirror (acts as xor8 on half-row-uniform values).
template<int CTRL>
__device__ __forceinline__ float dpp_add(float v) {
    int s = __builtin_amdgcn_update_dpp(0, __float_as_int(v), CTRL, 0xF, 0xF, true);
    return v + __int_as_float(s);
}

template<int CTRL>
__device__ __forceinline__ float dpp_min(float v) {
    int s = __builtin_amdgcn_update_dpp(0, __float_as_int(v), CTRL, 0xF, 0xF, true);
    return fminf(v, __int_as_float(s));
}

#define CLAMP01(v) __builtin_amdgcn_fmed3f((v), 0.0f, 1.0f)

// ---------------------------------------------------------------------------
// k0 (merged): blocks 0..255 precompute sigmoid(A), BwT, Cs, gs.
// Blocks 256..259 compute csum[d] = sum_n sigmoid(W_C[d][n]) in EXACTLY the
// op order of k2's slow path with h==1 (per-quad (c0+c1)+(c2+c3), balanced
// XOR tree off=1,2,4,8) — sigmoidf_dev(W_C[i]) is bitwise-identical to the
// Cs value k2 uses, so the substitution in k3 stays bit-exact.
// ---------------------------------------------------------------------------
__global__ __launch_bounds__(256) void k0_precompute(
        const float* __restrict__ A, const float* __restrict__ W_B,
        const float* __restrict__ W_C, const float* __restrict__ gamma,
        float* __restrict__ A_sig, float* __restrict__ BwT,
        float* __restrict__ Cs, float* __restrict__ gs,
        float* __restrict__ csum) {
    const int bid = blockIdx.x;
    const int t   = threadIdx.x;
    if (bid < 256) {
        int i = bid * 256 + t;
        A_sig[i] = sigmoidf_dev(A[i]);
        Cs[i]    = sigmoidf_dev(W_C[i]);
        int d = i >> 6, n = i & 63;                  // i = d*64 + n
        BwT[i] = sigmoidf_dev(W_B[n * D_MODEL + d]); // W_B is [N, D]
        if (i < D_MODEL) gs[i] = sigmoidf_dev(gamma[i]);
    } else {
        int d = (bid - 256) * 256 + t;               // 0..1023
        const float4* c = (const float4*)(W_C + (size_t)d * N_STATE);
        float w[16];
#pragma unroll
        for (int q = 0; q < 16; ++q) {
            float4 v = c[q];
            w[q] = (sigmoidf_dev(v.x) + sigmoidf_dev(v.y)) +
                   (sigmoidf_dev(v.z) + sigmoidf_dev(v.w));
        }
#pragma unroll
        for (int off = 1; off < 16; off <<= 1) {
            float tmp[16];
#pragma unroll
            for (int q = 0; q < 16; ++q) tmp[q] = w[q] + w[q ^ off];
#pragma unroll
            for (int q = 0; q < 16; ++q) w[q] = tmp[q];
        }
        csum[d] = w[0];
    }
}

// ---------------------------------------------------------------------------
// k1: bt[m][n] = sum_d x[m][d] * BwT[d][n]  (M=16384, K=1024, N=64, fp32)
// Round 7: round-6 was latency-bound at 1 wave/SIMD (VALUBusy 27%; grid 256
// x block 256 = 4 waves/CU). Fix: split-K within the block. Block = 512
// threads (8 waves); group g = t>>8 accumulates k in [g*512, g*512+512)
// sequentially (kt asc, kk asc — identical per-half order). Group 1 writes
// partials to LDS scalar planes (stride-1, conflict-free); group 0 adds,
// stores bt and btmin. Grid 256 -> 8 waves/CU, 2 waves/SIMD, still 2 B/FMA.
// ONE reassociation point per element ((sum lo-half)+(sum hi-half)): bt
// drift ~5e-4 on ~256; pred flips are output-neutral (SAT_T margin).
// btmin: fmin is exactly associative -> tree unchanged.
// ---------------------------------------------------------------------------
__global__ __launch_bounds__(512) void k1_bt_gemm(
        const float* __restrict__ x, const float* __restrict__ BwT,
        float* __restrict__ bt, float* __restrict__ btmin) {
    __shared__ float xs[2][2][16][68];   // [grp][buf][k][m(64)+4 pad]
    __shared__ float bs[2][2][16][64];   // [grp][buf][k][n]
    __shared__ float accb[16][256];      // group-1 partials, scalar planes

    const int t   = threadIdx.x;
    const int g   = t >> 8;           // k-half group
    const int tid = t & 255;
    const int r   = tid >> 4;         // 0..15 -> m rows r*4 .. r*4+3
    const int c   = tid & 15;         // 0..15 -> n quad c*4
    const int m0  = blockIdx.x * 64;
    const int kb  = g * 512;          // k base for this group

    const int sm  = tid >> 2;         // staging: m row 0..63
    const int sk4 = (tid & 3) * 4;    // staging: k quad 0,4,8,12

    float acc[4][4];
#pragma unroll
    for (int i = 0; i < 4; ++i)
#pragma unroll
        for (int j = 0; j < 4; ++j) acc[i][j] = 0.0f;

    // stage tile 0 into buf 0
    {
        float4 xv = *(const float4*)(x + (size_t)(m0 + sm) * D_MODEL + kb + sk4);
        float4 bv = *(const float4*)(BwT + (size_t)kb * N_STATE + tid * 4);
        xs[g][0][sk4 + 0][sm] = xv.x;
        xs[g][0][sk4 + 1][sm] = xv.y;
        xs[g][0][sk4 + 2][sm] = xv.z;
        xs[g][0][sk4 + 3][sm] = xv.w;
        *(float4*)(&bs[g][0][0][0] + tid * 4) = bv;
    }
    __syncthreads();

    for (int kt = 0; kt < 32; ++kt) {
        const int p = kt & 1;
        const bool more = (kt + 1 < 32);
        float4 xv, bv;
        if (more) {
            const int k0 = kb + (kt + 1) * 16;
            xv = *(const float4*)(x + (size_t)(m0 + sm) * D_MODEL + k0 + sk4);
            bv = *(const float4*)(BwT + (size_t)k0 * N_STATE + tid * 4);
        }

#pragma unroll
        for (int kk = 0; kk < 16; ++kk) {
            const float4 ap = *(const float4*)(&xs[g][p][kk][r * 4]);
            const float4 bq = *(const float4*)(&bs[g][p][kk][c * 4]);
            acc[0][0] = fmaf(ap.x, bq.x, acc[0][0]);
            acc[0][1] = fmaf(ap.x, bq.y, acc[0][1]);
            acc[0][2] = fmaf(ap.x, bq.z, acc[0][2]);
            acc[0][3] = fmaf(ap.x, bq.w, acc[0][3]);
            acc[1][0] = fmaf(ap.y, bq.x, acc[1][0]);
            acc[1][1] = fmaf(ap.y, bq.y, acc[1][1]);
            acc[1][2] = fmaf(ap.y, bq.z, acc[1][2]);
            acc[1][3] = fmaf(ap.y, bq.w, acc[1][3]);
            acc[2][0] = fmaf(ap.z, bq.x, acc[2][0]);
            acc[2][1] = fmaf(ap.z, bq.y, acc[2][1]);
            acc[2][2] = fmaf(ap.z, bq.z, acc[2][2]);
            acc[2][3] = fmaf(ap.z, bq.w, acc[2][3]);
            acc[3][0] = fmaf(ap.w, bq.x, acc[3][0]);
            acc[3][1] = fmaf(ap.w, bq.y, acc[3][1]);
            acc[3][2] = fmaf(ap.w, bq.z, acc[3][2]);
            acc[3][3] = fmaf(ap.w, bq.w, acc[3][3]);
        }

        if (more) {
            const int q = 1 - p;
            xs[g][q][sk4 + 0][sm] = xv.x;
            xs[g][q][sk4 + 1][sm] = xv.y;
            xs[g][q][sk4 + 2][sm] = xv.z;
            xs[g][q][sk4 + 3][sm] = xv.w;
            *(float4*)(&bs[g][q][0][0] + tid * 4) = bv;
        }
        __syncthreads();
    }

    // combine halves: group 1 publishes partials, group 0 reduces + stores
    if (g == 1) {
#pragma unroll
        for (int i = 0; i < 4; ++i)
#pragma unroll
            for (int j = 0; j < 4; ++j)
                accb[i * 4 + j][tid] = acc[i][j];
    }
    __syncthreads();
    if (g == 0) {
#pragma unroll
        for (int i = 0; i < 4; ++i) {
            float o0 = acc[i][0] + accb[i * 4 + 0][tid];
            float o1 = acc[i][1] + accb[i * 4 + 1][tid];
            float o2 = acc[i][2] + accb[i * 4 + 2][tid];
            float o3 = acc[i][3] + accb[i * 4 + 3][tid];
            *(float4*)(&bt[(size_t)(m0 + r * 4 + i) * N_STATE + c * 4]) =
                make_float4(o0, o1, o2, o3);
            // btmin: per-thread min of its 4 n's, then DPP min across the
            // aligned 16-lane row (lanes sharing r). min is exactly
            // associative -> tree semantics unchanged.
            float bm = fminf(fminf(o0, o1), fminf(o2, o3));
            bm = dpp_min<0xB1>(bm);  bm = dpp_min<0x4E>(bm);
            bm = dpp_min<0x141>(bm); bm = dpp_min<0x140>(bm);
            if (c == 0) btmin[m0 + r * 4 + i] = bm;
        }
    }
}

// ---------------------------------------------------------------------------
// k2: sequential scan, time-segmented 2x. grid 2048 = 16 batch x 64 dgroup x
// 2 segments -> 8 blocks/CU, 32 waves/CU.
// Saturation fast path (round-3, verified): pred(s,d) = x*max(btmin,0) >=
// SAT_T => h clamps to exactly 1.0f, y bitwise csum[d]; k2 stores only
// pred-false rows (~0.4%), k3 reconstructs the rest.
// Round 4: px transposed [chain][LPS]; 4-step groups take ONE float4 read +
// 3 min + 1 vote when the wave's quad is all-fast (~94%), falling back to
// the identical per-step path for mixed quads.
// ---------------------------------------------------------------------------
__global__ __launch_bounds__(256, 8) void k2_scan(
        const float* __restrict__ x, const float* __restrict__ bt,
        const float* __restrict__ btmin,
        const float* __restrict__ A_sig, const float* __restrict__ Cs,
        float* __restrict__ y_raw) {
    const int t    = threadIdx.x;
    const int lane = t & 63;
    const int wv   = t >> 6;
    const int nq   = lane & 15;            // n-quad -> n = nq*4
    const int cl   = wv * 4 + (lane >> 4); // chain within block, 0..15
    const int bid  = blockIdx.x;
    const int seg  = bid & 1;
    const int dg   = (bid >> 1) & 63;
    const int b    = bid >> 7;
    const int d0   = dg * 16;
    const int d    = d0 + cl;

    const int nWarm  = seg ? (WARM / CS) : 0;     // 4 or 0
    const int nTot   = nWarm + (SEGLEN / CS);     // 36 or 32
    const int sStart = seg * SEGLEN - nWarm * CS; // 0 or 448

    __shared__ __align__(16) float lbt [2][CS * 64];    // 2 x 4 KB bt tile
    __shared__ __align__(16) float lx  [2][CS * 16];    // 2 x 1 KB x[step][chain]
    __shared__ __align__(16) float lpxT[2][16 * LPS];   // 2 x 1.25 KB px[chain][step(+pad)]

    const float4 av = *(const float4*)(A_sig + (size_t)d * N_STATE + nq * 4);
    const float4 cv = *(const float4*)(Cs    + (size_t)d * N_STATE + nq * 4);

    float h0 = 0.f, h1 = 0.f, h2 = 0.f, h3 = 0.f;

    const float* btp  = bt    + (size_t)b * SEQ * N_STATE + (size_t)sStart * N_STATE;
    const float* btmp = btmin + (size_t)b * SEQ + sStart;
    const float* xpp  = x + (size_t)b * SEQ * D_MODEL + (size_t)sStart * D_MODEL + d0;
    float* ystore = y_raw + (size_t)b * SEQ * D_MODEL + (size_t)seg * SEGLEN * D_MODEL + d;

    const int xst = t >> 4;          // staging: step 0..15
    const int xdd = t & 15;          // staging: chain

    // stage chunk 0 into buf 0
    {
        float4 b4 = *(const float4*)(btp + t * 4);
        float  xv = xpp[(size_t)xst * D_MODEL + xdd];
        float  bm = fmaxf(btmp[xst], 0.f);   // clamp: pred => bm>0 and x>0
        *(float4*)(&lbt[0][t * 4]) = b4;
        lx[0][t] = xv;
        lpxT[0][xdd * LPS + xst] = xv * bm;
    }
    btp  += CS * N_STATE;
    btmp += CS;
    xpp  += (size_t)CS * D_MODEL;
    __syncthreads();

    for (int ch = 0; ch < nTot; ++ch) {
        const int p = ch & 1;
        float4 nb; float nx, npx;
        const bool more = (ch + 1 < nTot);
        if (more) {
            nb  = *(const float4*)(btp + t * 4);
            nx  = xpp[(size_t)xst * D_MODEL + xdd];
            npx = nx * fmaxf(btmp[xst], 0.f);
            btp  += CS * N_STATE;
            btmp += CS;
            xpp  += (size_t)CS * D_MODEL;
        }

        const float* Lb = lbt[p];
        const float* Lx = lx [p];
        const float* Lp = &lpxT[p][cl * LPS];   // this lane's chain, 16 steps

        if (ch < nWarm) {
#pragma unroll
            for (int g = 0; g < 4; ++g) {
                const float4 pq = *(const float4*)(Lp + g * 4);
                const float qmin = fminf(fminf(pq.x, pq.y), fminf(pq.z, pq.w));
                if (__all(qmin >= SAT_T)) { h0 = h1 = h2 = h3 = 1.f; continue; }
                const float pmv[4] = {pq.x, pq.y, pq.z, pq.w};
#pragma unroll
                for (int j = 0; j < 4; ++j) {
                    const int i = g * 4 + j;
                    const float pm = pmv[j];
                    if (__all(pm >= SAT_T)) { h0 = h1 = h2 = h3 = 1.f; continue; }
                    const float  xt = Lx[i * 16 + cl];
                    const float4 bv = *(const float4*)(Lb + i * 64 + nq * 4);
                    h0 = CLAMP01(fmaf(h0, av.x, bv.x * xt));
                    h1 = CLAMP01(fmaf(h1, av.y, bv.y * xt));
                    h2 = CLAMP01(fmaf(h2, av.z, bv.z * xt));
                    h3 = CLAMP01(fmaf(h3, av.w, bv.w * xt));
                }
            }
        } else {
#pragma unroll
            for (int g = 0; g < 4; ++g) {
                const float4 pq = *(const float4*)(Lp + g * 4);
                const float qmin = fminf(fminf(pq.x, pq.y), fminf(pq.z, pq.w));
                if (__all(qmin >= SAT_T)) { h0 = h1 = h2 = h3 = 1.f; continue; }
                const float pmv[4] = {pq.x, pq.y, pq.z, pq.w};
#pragma unroll
                for (int j = 0; j < 4; ++j) {
                    const int i = g * 4 + j;
                    const float pm = pmv[j];
                    if (__all(pm >= SAT_T)) { h0 = h1 = h2 = h3 = 1.f; continue; }
                    const float  xt = Lx[i * 16 + cl];
                    const float4 bv = *(const float4*)(Lb + i * 64 + nq * 4);
                    h0 = CLAMP01(fmaf(h0, av.x, bv.x * xt));
                    h1 = CLAMP01(fmaf(h1, av.y, bv.y * xt));
                    h2 = CLAMP01(fmaf(h2, av.z, bv.z * xt));
                    h3 = CLAMP01(fmaf(h3, av.w, bv.w * xt));
                    float y = fmaf(h0, cv.x, h1 * cv.y) + fmaf(h2, cv.z, h3 * cv.w);
                    y = dpp_add<0xB1>(y);
                    y = dpp_add<0x4E>(y);
                    y = dpp_add<0x141>(y);
                    y = dpp_add<0x140>(y);
                    // store only pred-false rows (row-uniform condition);
                    // pred-true rows are reconstructed as csum[d] in k3.
                    if (nq == 0 && !(pm >= SAT_T)) ystore[(size_t)i * D_MODEL] = y;
                }
            }
            ystore += (size_t)CS * D_MODEL;
        }

        if (more) {
            const int q = 1 - p;
            *(float4*)(&lbt[q][t * 4]) = nb;
            lx[q][t] = nx;
            lpxT[q][xdd * LPS + xst] = npx;
        }
        __syncthreads();
    }
}

// ---------------------------------------------------------------------------
// k3: per (b,s) row of 1024: reconstruct y (pred ? csum[d] : stored y_raw),
// two-pass layernorm over d, scale by gs, add residual x, clip. In-place.
// Single conditional float4 load (taken by ~1.6% of lanes).
// ---------------------------------------------------------------------------
__global__ __launch_bounds__(256, 1) void k3_norm(
        const float* __restrict__ x, const float* __restrict__ gs,
        const float* __restrict__ btmin, const float* __restrict__ csum,
        float* __restrict__ y) {
    const int row = blockIdx.x;           // b*SEQ + s
    const int t   = threadIdx.x;
    const size_t base = (size_t)row * D_MODEL + t * 4;
    const float bm = fmaxf(btmin[row], 0.f);   // same clamp+product as k2

    float4 xv  = *(const float4*)(x + base);
    float4 cs4 = *(const float4*)(csum + t * 4);
    const bool p0 = (xv.x * bm >= SAT_T);
    const bool p1 = (xv.y * bm >= SAT_T);
    const bool p2 = (xv.z * bm >= SAT_T);
    const bool p3 = (xv.w * bm >= SAT_T);
    float y0 = cs4.x, y1 = cs4.y, y2 = cs4.z, y3 = cs4.w;
    if (!(p0 && p1 && p2 && p3)) {
        float4 ld = *(const float4*)(y + base);
        if (!p0) y0 = ld.x;
        if (!p1) y1 = ld.y;
        if (!p2) y2 = ld.z;
        if (!p3) y3 = ld.w;
    }

    float s1 = (y0 + y1) + (y2 + y3);
#pragma unroll
    for (int off = 32; off > 0; off >>= 1) s1 += __shfl_xor(s1, off);

    __shared__ float red[8];
    const int w = t >> 6;
    if ((t & 63) == 0) red[w] = s1;
    __syncthreads();
    const float mu = (red[0] + red[1] + red[2] + red[3]) * (1.0f / (float)D_MODEL);

    const float dx0 = y0 - mu, dx1 = y1 - mu, dx2 = y2 - mu, dx3 = y3 - mu;
    float s2 = (dx0 * dx0 + dx1 * dx1) + (dx2 * dx2 + dx3 * dx3);
#pragma unroll
    for (int off = 32; off > 0; off >>= 1) s2 += __shfl_xor(s2, off);
    if ((t & 63) == 0) red[4 + w] = s2;
    __syncthreads();
    const float var = (red[4] + red[5] + red[6] + red[7]) * (1.0f / (float)D_MODEL);
    const float rs  = 1.0f / sqrtf(var + 1e-5f);

    float4 gv = *(const float4*)(gs + t * 4);
    float4 o;
    o.x = fminf(fmaxf(dx0 * rs * gv.x + xv.x, 0.f), 1.f);
    o.y = fminf(fmaxf(dx1 * rs * gv.y + xv.y, 0.f), 1.f);
    o.z = fminf(fmaxf(dx2 * rs * gv.z + xv.z, 0.f), 1.f);
    o.w = fminf(fmaxf(dx3 * rs * gv.w + xv.w, 0.f), 1.f);
    *(float4*)(y + base) = o;
}

// ---------------------------------------------------------------------------
extern "C" void kernel_launch(void* const* d_in, const int* in_sizes, int n_in,
                              void* d_out, int out_size, void* d_ws, size_t ws_size,
                              hipStream_t stream) {
    (void)in_sizes; (void)n_in; (void)out_size; (void)ws_size;
    const float* x     = (const float*)d_in[0];
    const float* A     = (const float*)d_in[1];
    const float* W_B   = (const float*)d_in[2];
    const float* W_C   = (const float*)d_in[3];
    const float* gamma = (const float*)d_in[4];
    float* out = (float*)d_out;
    float* ws  = (float*)d_ws;

    float* bt    = ws;                                       // 1048576 floats
    float* A_sig = ws + 1048576;                             // 65536
    float* BwT   = ws + 1048576 + 65536;                     // 65536
    float* Cs    = ws + 1048576 + 2 * 65536;                 // 65536
    float* gs    = ws + 1048576 + 3 * 65536;                 // 1024
    float* btmin = ws + 1048576 + 3 * 65536 + 1024;          // 16384
    float* csum  = ws + 1048576 + 3 * 65536 + 1024 + 16384;  // 1024

    k0_precompute<<<dim3(260), dim3(256), 0, stream>>>(A, W_B, W_C, gamma,
                                                       A_sig, BwT, Cs, gs, csum);
    k1_bt_gemm<<<dim3(256), dim3(512), 0, stream>>>(x, BwT, bt, btmin);
    k2_scan<<<dim3(2048), dim3(256), 0, stream>>>(x, bt, btmin, A_sig, Cs, out);
    k3_norm<<<dim3(BATCH * SEQ), dim3(256), 0, stream>>>(x, gs, btmin, csum, out);
}